// Round 3
// baseline (155.834 us; speedup 1.0000x reference)
//
#include <hip/hip_runtime.h>
#include <hip/hip_cooperative_groups.h>
#include <stdint.h>

namespace cg = cooperative_groups;

#define BB   32
#define HH   64
#define WW   2048
#define HOUT 128      // 2*(HH-1)+2
#define NBLK 1024
#define NTHR 256

__global__ void __launch_bounds__(NTHR, 4)
k_fused(const float* __restrict__ x, float* __restrict__ out,
        float* __restrict__ partial) {
    __shared__ float smem[4];
    const int tid = threadIdx.x;
    const int gid = blockIdx.x * NTHR + tid;
    const int lane = tid & 63, wid = tid >> 6;

    // ---- phase 1: per-block min over x (grid-stride, float4) ----
    const float4* x4 = (const float4*)x;
    const int n4 = BB * HH * WW / 4;          // 1,048,576
    float m = 3.4e38f;
    for (int i = gid; i < n4; i += NBLK * NTHR) {
        float4 v = x4[i];
        m = fminf(fminf(v.x, v.y), fminf(fminf(v.z, v.w), m));
    }
    #pragma unroll
    for (int off = 32; off > 0; off >>= 1)
        m = fminf(m, __shfl_down(m, off, 64));
    if (lane == 0) smem[wid] = m;
    __syncthreads();
    if (tid == 0) {
        float bm = fminf(fminf(smem[0], smem[1]), fminf(smem[2], smem[3]));
        // agent-scope release store: visible across XCD L2s
        __hip_atomic_store(&partial[blockIdx.x], bm, __ATOMIC_RELEASE,
                           __HIP_MEMORY_SCOPE_AGENT);
    }

    cg::this_grid().sync();

    // ---- phase 2: every block reduces the 1024 partials ----
    float pm;
    {
        float p0 = __hip_atomic_load(&partial[tid],       __ATOMIC_RELAXED, __HIP_MEMORY_SCOPE_AGENT);
        float p1 = __hip_atomic_load(&partial[tid + 256], __ATOMIC_RELAXED, __HIP_MEMORY_SCOPE_AGENT);
        float p2 = __hip_atomic_load(&partial[tid + 512], __ATOMIC_RELAXED, __HIP_MEMORY_SCOPE_AGENT);
        float p3 = __hip_atomic_load(&partial[tid + 768], __ATOMIC_RELAXED, __HIP_MEMORY_SCOPE_AGENT);
        pm = fminf(fminf(p0, p1), fminf(p2, p3));
    }
    #pragma unroll
    for (int off = 32; off > 0; off >>= 1)
        pm = fminf(pm, __shfl_down(pm, off, 64));
    __syncthreads();               // smem reuse guard
    if (lane == 0) smem[wid] = pm;
    __syncthreads();
    // padding zeros are part of the window tensor -> gmin = min(min(x), 0)
    const float gmin = fminf(fminf(fminf(smem[0], smem[1]),
                                   fminf(smem[2], smem[3])), 0.0f);

    const float BASE_D = 0.49306869139523979f;  // exp(-sqrt(2)/2)
    const float BASE_C = 0.60653065971263342f;  // exp(-0.5)

    // ---- phase 3: outputs (grid-stride, float4) ----
    const int total4 = BB * HOUT * WW / 4;      // 2,097,152
    for (int i = gid; i < total4; i += NBLK * NTHR) {
        int b   = i >> 16;          // 65536 float4 per batch image
        int rem = i & 65535;
        int ho  = rem >> 9;         // 512 float4 per row
        int w0  = (rem & 511) << 2;

        float4* o4 = (float4*)(out + ((size_t)b * HOUT + ho) * WW + w0);
        int h = ho >> 1;            // even: src row; odd: pixel row; 126,127 -> 63
        const float* rA = x + ((size_t)b * HH + h) * WW + w0;

        if ((ho & 1) == 0 || ho == 127) {
            *o4 = *(const float4*)rA;
            continue;
        }

        const float* rB = rA + WW;
        float4 a  = *(const float4*)rA;
        float4 c4 = *(const float4*)rB;
        float aL = (w0 > 0)      ? rA[-1] : 0.0f;
        float bL = (w0 > 0)      ? rB[-1] : 0.0f;
        float aR = (w0 + 4 < WW) ? rA[4]  : 0.0f;
        float bR = (w0 + 4 < WW) ? rB[4]  : 0.0f;

        float av[6] = {aL, a.x, a.y, a.z, a.w, aR};
        float bv[6] = {bL, c4.x, c4.y, c4.z, c4.w, bR};

        float4 res;
        float* rp = &res.x;
        #pragma unroll
        for (int c = 0; c < 4; ++c) {
            float num = 0.0f, den = 0.0f;
            float vs[6] = {av[c], av[c + 1], av[c + 2],
                           bv[c], bv[c + 1], bv[c + 2]};
            const float bs[6] = {BASE_D, BASE_C, BASE_D, BASE_D, BASE_C, BASE_D};
            #pragma unroll
            for (int k = 0; k < 6; ++k) {
                float wv = vs[k];
                float e  = __expf(wv - gmin);
                float wi = bs[k] * 2.0f * __builtin_amdgcn_rcpf(1.0f + e);
                wi = (wv != 0.0f) ? wi : 0.0f;
                num += wv * wi;
                den += wi;
            }
            den = (den == 0.0f) ? 1.0f : den;
            rp[c] = num * __builtin_amdgcn_rcpf(den);
        }
        *o4 = res;
    }
}

extern "C" void kernel_launch(void* const* d_in, const int* in_sizes, int n_in,
                              void* d_out, int out_size, void* d_ws, size_t ws_size,
                              hipStream_t stream) {
    const float* x = (const float*)d_in[0];
    float* out = (float*)d_out;
    float* partial = (float*)d_ws;   // 1024 floats = 4 KiB of scratch

    void* args[] = {(void*)&x, (void*)&out, (void*)&partial};
    hipLaunchCooperativeKernel((const void*)k_fused, dim3(NBLK), dim3(NTHR),
                               args, 0, stream);
}

// Round 5
// 21.678 us; speedup vs baseline: 7.1887x; 7.1887x over previous
//
#include <hip/hip_runtime.h>
#include <stdint.h>

#define BB   32
#define HH   64
#define WW   2048
#define HOUT 128     // 2*(HH-1)+2
#define NB1  1024
#define NT   256

typedef float f4 __attribute__((ext_vector_type(4)));

// ---- K1: global-min partials + copy rows ---------------------------------
// Reads all of x once (f4). Accumulates per-block min -> partial[blk].
// Each x row h is also an output copy row: out[2h] = x[h] (h=0..62 -> even
// rows 0..124; h=63 -> rows 126 AND 127).
__global__ void __launch_bounds__(NT)
k1_min_copy(const float* __restrict__ x, float* __restrict__ out,
            float* __restrict__ partial) {
    const int tid = threadIdx.x;
    const f4* x4 = (const f4*)x;
    float m = 3.4e38f;

    int i = blockIdx.x * NT + tid;
    #pragma unroll
    for (int it = 0; it < (BB * HH * WW / 4) / (NB1 * NT); ++it, i += NB1 * NT) {
        f4 v = x4[i];
        m = fminf(fminf(v.x, v.y), fminf(fminf(v.z, v.w), m));

        int b   = i >> 15;        // HH*WW/4 = 32768 f4 per batch image
        int rem = i & 32767;
        int h   = rem >> 9;       // 512 f4 per row
        int wq  = rem & 511;

        f4* o = (f4*)(out + ((size_t)(b * HOUT) + 2 * h) * WW) + wq;
        __builtin_nontemporal_store(v, o);
        if (h == 63) {            // duplicate last row (2*63=126 above, plus 127)
            f4* o2 = (f4*)(out + ((size_t)(b * HOUT) + 127) * WW) + wq;
            __builtin_nontemporal_store(v, o2);
        }
    }

    // wave-64 shuffle reduce, then LDS combine
    #pragma unroll
    for (int off = 32; off > 0; off >>= 1)
        m = fminf(m, __shfl_down(m, off, 64));
    __shared__ float smem[4];
    if ((tid & 63) == 0) smem[tid >> 6] = m;
    __syncthreads();
    if (tid == 0)
        partial[blockIdx.x] =
            fminf(fminf(smem[0], smem[1]), fminf(smem[2], smem[3]));
}

// ---- K2: odd (interpolated) rows -----------------------------------------
// grid = BB * 63 * 2 = 4032 blocks; each block does half of one odd row.
__global__ void __launch_bounds__(NT)
k2_pixels(const float* __restrict__ x, float* __restrict__ out,
          const float* __restrict__ partial) {
    __shared__ float smem[4];
    const int tid = threadIdx.x;

    // block-wide reduction of the 1024 partials (L2-resident after K1)
    float p = fminf(fminf(partial[tid], partial[tid + 256]),
                    fminf(partial[tid + 512], partial[tid + 768]));
    #pragma unroll
    for (int off = 32; off > 0; off >>= 1)
        p = fminf(p, __shfl_down(p, off, 64));
    if ((tid & 63) == 0) smem[tid >> 6] = p;
    __syncthreads();
    // padding zeros are part of the window tensor -> gmin = min(min(x), 0)
    const float gmin = fminf(
        fminf(fminf(smem[0], smem[1]), fminf(smem[2], smem[3])), 0.0f);

    int blk = blockIdx.x;
    int b   = blk / 126;          // 63 odd rows * 2 half-rows per batch
    int r   = blk - b * 126;
    int h   = r >> 1;             // x top row 0..62
    int w0  = ((r & 1) << 10) + (tid << 2);   // half*1024 + tid*4

    const float* rA = x + ((size_t)(b * HH) + h) * WW + w0;
    const float* rB = rA + WW;

    f4 a  = *(const f4*)rA;
    f4 c4 = *(const f4*)rB;
    float aL = (w0 > 0)      ? rA[-1] : 0.0f;
    float bL = (w0 > 0)      ? rB[-1] : 0.0f;
    float aR = (w0 + 4 < WW) ? rA[4]  : 0.0f;
    float bR = (w0 + 4 < WW) ? rB[4]  : 0.0f;

    float av[6] = {aL, a.x, a.y, a.z, a.w, aR};
    float bv[6] = {bL, c4.x, c4.y, c4.z, c4.w, bR};

    const float BASE_D = 0.49306869139523979f;  // exp(-sqrt(2)/2)
    const float BASE_C = 0.60653065971263342f;  // exp(-0.5)

    f4 res;
    #pragma unroll
    for (int c = 0; c < 4; ++c) {
        float num = 0.0f, den = 0.0f;
        float vs[6] = {av[c], av[c + 1], av[c + 2],
                       bv[c], bv[c + 1], bv[c + 2]};
        const float bs[6] = {BASE_D, BASE_C, BASE_D, BASE_D, BASE_C, BASE_D};
        #pragma unroll
        for (int k = 0; k < 6; ++k) {
            float wv = vs[k];
            float e  = __expf(wv - gmin);
            float wi = bs[k] * 2.0f * __builtin_amdgcn_rcpf(1.0f + e);
            wi = (wv != 0.0f) ? wi : 0.0f;
            num += wv * wi;
            den += wi;
        }
        den = (den == 0.0f) ? 1.0f : den;
        res[c] = num * __builtin_amdgcn_rcpf(den);
    }

    f4* o = (f4*)(out + ((size_t)(b * HOUT) + 2 * h + 1) * WW + w0);
    __builtin_nontemporal_store(res, o);
}

extern "C" void kernel_launch(void* const* d_in, const int* in_sizes, int n_in,
                              void* d_out, int out_size, void* d_ws, size_t ws_size,
                              hipStream_t stream) {
    const float* x = (const float*)d_in[0];
    float* out = (float*)d_out;
    float* partial = (float*)d_ws;   // 1024 floats

    hipLaunchKernelGGL(k1_min_copy, dim3(NB1), dim3(NT), 0, stream,
                       x, out, partial);
    hipLaunchKernelGGL(k2_pixels, dim3(BB * 63 * 2), dim3(NT), 0, stream,
                       x, out, partial);
}